// Round 10
// baseline (180.067 us; speedup 1.0000x reference)
//
#include <hip/hip_runtime.h>
#include <stdint.h>

#define D_MODEL 1024
#define NH      16
#define DKH     64
#define SEQLEN  2048
#define BATCH   2
#define KDIM    1024   // inner dim of all projections

typedef __attribute__((ext_vector_type(8))) short          short8;   // 8 bf16 (4 VGPRs)
typedef __attribute__((ext_vector_type(4))) short          bf16x4;   // 4 bf16 (2 VGPRs)
typedef __attribute__((ext_vector_type(8))) unsigned short ushort8;
typedef __attribute__((ext_vector_type(4))) unsigned short usht4;    // 'ushort4' is taken by HIP
typedef __attribute__((ext_vector_type(4))) float          f32x4;

// exp2(q·k) where q pre-scaled by 0.125*log2(e) == exp(q·k/8)
#define QSCALE 0.18033688011112042f
#define OPART_STRIDE 4194304   // floats per g-half: 32*2048*64

// ---------- helpers ----------
__device__ __forceinline__ unsigned short f2bf(float f) {
    union { float f; unsigned u; } v; v.f = f;
    unsigned u = v.u;
    unsigned r = (u + 0x7FFFu + ((u >> 16) & 1u)) >> 16;   // RNE
    return (unsigned short)r;
}
__device__ __forceinline__ unsigned fbits(float f) {
    union { float f; unsigned u; } v; v.f = f; return v.u;
}

__device__ __forceinline__ void gload_lds16(const unsigned short* g, unsigned short* l) {
    __builtin_amdgcn_global_load_lds(
        (__attribute__((address_space(1))) void*)(g),
        (__attribute__((address_space(3))) void*)(l), 16, 0, 0);
}

// ---------- kernel 0: fp32 -> bf16 convert (5 tensors) + RoPE cos/sin table ----------
__global__ void cvt_all(const float* __restrict__ X,  const float* __restrict__ Wq,
                        const float* __restrict__ Wk, const float* __restrict__ Wv,
                        const float* __restrict__ Wo, const int* __restrict__ pos,
                        unsigned short* __restrict__ Xb,  unsigned short* __restrict__ Wqb,
                        unsigned short* __restrict__ Wkb, unsigned short* __restrict__ Wvb,
                        unsigned short* __restrict__ Wob, float2* __restrict__ tbl) {
    const int z = blockIdx.y;
    if (z == 5) {
        int i = blockIdx.x * 256 + threadIdx.x;   // tbl[s][j], 2048*32 entries
        if (i < 65536) {
            int s = i >> 5, j = i & 31;
            float freq = expf(-((float)(2 * j) * (1.0f / 64.0f)) * 9.210340371976184f);
            float ang = (float)pos[s] * freq;
            float sn, cn;
            sincosf(ang, &sn, &cn);
            tbl[i] = make_float2(cn, sn);
        }
        return;
    }
    const float* src; unsigned short* dst; int n;
    if (z == 0)      { src = X;  dst = Xb;  n = 4194304; }
    else if (z == 1) { src = Wq; dst = Wqb; n = 1048576; }
    else if (z == 2) { src = Wk; dst = Wkb; n = 1048576; }
    else if (z == 3) { src = Wv; dst = Wvb; n = 1048576; }
    else             { src = Wo; dst = Wob; n = 1048576; }
    int i = (blockIdx.x * 256 + threadIdx.x) * 8;
    if (i >= n) return;
    float4 a = *(const float4*)(src + i);
    float4 b = *(const float4*)(src + i + 4);
    ushort8 o;
    o[0] = f2bf(a.x); o[1] = f2bf(a.y); o[2] = f2bf(a.z); o[3] = f2bf(a.w);
    o[4] = f2bf(b.x); o[5] = f2bf(b.y); o[6] = f2bf(b.z); o[7] = f2bf(b.w);
    *(ushort8*)(dst + i) = o;
}

// ---------- shared GEMM core: C[128x128] = A[m0:,:] * W[n0:,:]^T, K=1024, BK=32 ----------
__device__ __forceinline__ void gemm_core_128(
    const unsigned short* __restrict__ A, const unsigned short* __restrict__ W,
    unsigned short* a_lds, unsigned short* b_lds,
    int m0, int n0, f32x4 acc[4][4])
{
    const int tid  = threadIdx.x;
    const int lane = tid & 63;
    const int w    = tid >> 6;
    const int quad = lane >> 4;
    const int l16  = lane & 15;
    const int wm   = w & 1, wn = w >> 1;

    const int srow = lane >> 2;        // 0..15 within 16-row chunk
    const int scol = (lane & 3) * 8;   // k-offset in elems

    #pragma unroll
    for (int mi = 0; mi < 4; mi++)
        #pragma unroll
        for (int ni = 0; ni < 4; ni++) {
            f32x4 z = {0.f, 0.f, 0.f, 0.f};
            acc[mi][ni] = z;
        }

    for (int kk = 0; kk < KDIM; kk += 32) {
        __syncthreads();
        #pragma unroll
        for (int i = 0; i < 2; ++i) {
            int c = 2 * w + i;          // chunk: 16 rows x 32 k (1KB)
            gload_lds16(A + (size_t)(m0 + c * 16 + srow) * KDIM + kk + scol, &a_lds[c * 512]);
            gload_lds16(W + (size_t)(n0 + c * 16 + srow) * KDIM + kk + scol, &b_lds[c * 512]);
        }
        __syncthreads();

        short8 af[4], bf[4];
        #pragma unroll
        for (int i = 0; i < 4; i++) {
            af[i] = *(const short8*)&a_lds[(wm * 64 + i * 16 + l16) * 32 + quad * 8];
            bf[i] = *(const short8*)&b_lds[(wn * 64 + i * 16 + l16) * 32 + quad * 8];
        }
        #pragma unroll
        for (int mi = 0; mi < 4; mi++)
            #pragma unroll
            for (int ni = 0; ni < 4; ni++)
                acc[mi][ni] = __builtin_amdgcn_mfma_f32_16x16x32_bf16(af[mi], bf[ni], acc[mi][ni], 0, 0, 0);
    }
}

// ---------- kernel 1: QKV projection + fused RoPE (Q,K) + V^T transpose-store ----------
__global__ __launch_bounds__(256, 2)
void gemm_qkv(const unsigned short* __restrict__ X,
              const unsigned short* __restrict__ Wq,
              const unsigned short* __restrict__ Wk,
              const unsigned short* __restrict__ Wv,
              const float2* __restrict__ tbl,
              unsigned short* __restrict__ q_ws,
              unsigned short* __restrict__ k_ws,
              unsigned short* __restrict__ v_ws)
{
    __shared__ __align__(16) unsigned short a_lds[128 * 32];
    __shared__ __align__(16) unsigned short b_lds[128 * 32];
    __shared__ __align__(16) unsigned short t_lds[32 * 136];   // V transpose staging

    const int z = blockIdx.z;
    const unsigned short* W = (z == 0) ? Wq : ((z == 1) ? Wk : Wv);
    const int m0 = blockIdx.x * 128, n0 = blockIdx.y * 128;

    f32x4 acc[4][4];
    gemm_core_128(X, W, a_lds, b_lds, m0, n0, acc);

    const int tid  = threadIdx.x;
    const int lane = tid & 63;
    const int w    = tid >> 6;
    const int quad = lane >> 4;
    const int l16  = lane & 15;
    const int wm   = w & 1, wn = w >> 1;

    if (z == 2) {
        // ---- V: transpose 128x128 tile through LDS, store [bh][d][s] coalesced ----
        const int bx = m0 >> 11;                 // batch
        const int c_local_w = wn * 16 + l16;     // writer column slot 0..31
        const int rd_c = tid >> 3;               // reader column slot 0..31
        const int rd_s = (tid & 7) * 16;         // reader s-offset
        #pragma unroll
        for (int ni = 0; ni < 4; ni++) {
            if (ni > 0) __syncthreads();         // prior pass reads done
            #pragma unroll
            for (int mi = 0; mi < 4; mi++) {
                usht4 v4;
                #pragma unroll
                for (int r = 0; r < 4; r++) v4[r] = f2bf(acc[mi][ni][r]);
                *(usht4*)&t_lds[c_local_w * 136 + wm * 64 + mi * 16 + quad * 4] = v4;
            }
            __syncthreads();
            int col = n0 + (rd_c >> 4) * 64 + ni * 16 + (rd_c & 15);
            int h = col >> 6, d = col & 63;
            size_t base = (size_t)(bx * NH + h) * DKH * SEQLEN + (size_t)d * SEQLEN
                        + (m0 & 2047) + rd_s;
            ushort8 x0 = *(ushort8*)&t_lds[rd_c * 136 + rd_s];
            ushort8 x1 = *(ushort8*)&t_lds[rd_c * 136 + rd_s + 8];
            *(ushort8*)&v_ws[base]     = x0;
            *(ushort8*)&v_ws[base + 8] = x1;
        }
    } else {
        // ---- Q/K: fused RoPE on fp32 acc, then round once ----
        unsigned short* dst = (z == 0) ? q_ws : k_ws;
        const float sc = (z == 0) ? QSCALE : 1.0f;
        #pragma unroll
        for (int mi = 0; mi < 4; mi++)
            #pragma unroll
            for (int ni = 0; ni < 4; ni++)
                #pragma unroll
                for (int r = 0; r < 4; r++) {
                    int row = m0 + wm * 64 + mi * 16 + quad * 4 + r;
                    int col = n0 + wn * 64 + ni * 16 + l16;
                    int b = row >> 11, s = row & 2047;
                    int h = col >> 6,  d = col & 63;
                    float val = acc[mi][ni][r];
                    float other = __shfl_xor(val, 1);     // RoPE partner: col^1 == lane^1
                    float2 cs = tbl[s * 32 + (d >> 1)];
                    float rv = (d & 1) ? (other * cs.y + val * cs.x)
                                       : (val * cs.x - other * cs.y);
                    dst[(size_t)(b * NH + h) * SEQLEN * DKH + (size_t)s * DKH + d] =
                        f2bf(rv * sc);
                }
    }
}

// ---------- kernel 2: split-K causal flash attention (S^T trick; 128q x 128k) ----------
// grid (bh=32, p=8, g=2): 512 blocks = 2/CU -> two independent blocks per CU interleave
// past each other's barrier drains. Half g processes key-tiles t ≡ g (mod 2).
// No-max softmax makes partials ADDITIVE: O = (O_a+O_b)/(l_a+l_b) -> trivial combine.
// id%8 = bh%8 for both g -> XCD L2 locality preserved.
__global__ __launch_bounds__(256, 2)
void attn_kernel(const unsigned short* __restrict__ q_ws,
                 const unsigned short* __restrict__ k_ws,
                 const unsigned short* __restrict__ v_ws,
                 float* __restrict__ o_part,
                 float* __restrict__ l_part)
{
    __shared__ __align__(16) unsigned short k_lds[128 * 72];       // [key][d] pad->72
    __shared__ __align__(16) unsigned short v_lds[64 * 136];       // [d][key] pad->136

    const int bh  = blockIdx.x;
    const int p   = blockIdx.y;         // 0..7
    const int g   = blockIdx.z;         // 0..1 key-half
    const int tid = threadIdx.x, lane = tid & 63, w = tid >> 6;
    const int quad = lane >> 4, l16 = lane & 15;

    const size_t kqbase = (size_t)bh * SEQLEN * DKH;
    const size_t vbase  = (size_t)bh * DKH * SEQLEN;

    const int krow = tid >> 3, kcol = (tid & 7) * 8;
    const int vrow = tid >> 4, vcol = (tid & 15) * 8;

    #pragma unroll
    for (int phase = 0; phase < 2; ++phase) {
        const int qt2 = (phase == 0) ? (15 - p) : p;
        const int q0  = qt2 * 128;
        const int nt  = qt2 + 1;              // # of 128-key tiles
        const int qwbase = q0 + w * 32;       // this wave's 32 queries

        short8 aq[2][2];
        #pragma unroll
        for (int st = 0; st < 2; st++)
            #pragma unroll
            for (int kc = 0; kc < 2; kc++)
                aq[st][kc] = *(const short8*)(q_ws + kqbase +
                    (size_t)(qwbase + st * 16 + l16) * DKH + kc * 32 + quad * 8);

        f32x4 o_acc[2][4];
        #pragma unroll
        for (int st = 0; st < 2; st++)
            #pragma unroll
            for (int df = 0; df < 4; df++) { f32x4 z = {0.f,0.f,0.f,0.f}; o_acc[st][df] = z; }
        float lsum[2] = {0.f, 0.f};

        // prefetch first tile of this half
        ushort8 kreg[4], vreg[4];
        if (g < nt) {
            int sp = g * 128;
            #pragma unroll
            for (int rr = 0; rr < 4; ++rr) {
                kreg[rr] = *(const ushort8*)(k_ws + kqbase + (size_t)(sp + krow + rr * 32) * DKH + kcol);
                vreg[rr] = *(const ushort8*)(v_ws + vbase + (size_t)(vrow + rr * 16) * SEQLEN + sp + vcol);
            }
        }

        for (int t = g; t < nt; t += 2) {
            const int s0 = t * 128;
            __syncthreads();
            #pragma unroll
            for (int rr = 0; rr < 4; ++rr) {
                *(ushort8*)&k_lds[(krow + rr * 32) * 72 + kcol]  = kreg[rr];
                *(ushort8*)&v_lds[(vrow + rr * 16) * 136 + vcol] = vreg[rr];
            }
            __syncthreads();
            if (t + 2 < nt) {
                int s1 = s0 + 256;
                #pragma unroll
                for (int rr = 0; rr < 4; ++rr) {
                    kreg[rr] = *(const ushort8*)(k_ws + kqbase + (size_t)(s1 + krow + rr * 32) * DKH + kcol);
                    vreg[rr] = *(const ushort8*)(v_ws + vbase + (size_t)(vrow + rr * 16) * SEQLEN + s1 + vcol);
                }
            }

            const bool diag = (t == nt - 1);
            #pragma unroll
            for (int nf = 0; nf < 8; nf++) {
                short8 kf0 = *(const short8*)&k_lds[(nf * 16 + l16) * 72 + 0 * 32 + quad * 8];
                short8 kf1 = *(const short8*)&k_lds[(nf * 16 + l16) * 72 + 1 * 32 + quad * 8];
                bf16x4 vf[4];
                #pragma unroll
                for (int df = 0; df < 4; df++)
                    vf[df] = *(const bf16x4*)&v_lds[(df * 16 + l16) * 136 + nf * 16 + quad * 4];

                #pragma unroll
                for (int st = 0; st < 2; st++) {
                    f32x4 s = {0.f,0.f,0.f,0.f};
                    s = __builtin_amdgcn_mfma_f32_16x16x32_bf16(kf0, aq[st][0], s, 0, 0, 0);
                    s = __builtin_amdgcn_mfma_f32_16x16x32_bf16(kf1, aq[st][1], s, 0, 0, 0);

                    if (diag) {
                        int qg = qwbase + st * 16 + l16;
                        int kg = s0 + nf * 16 + quad * 4;
                        #pragma unroll
                        for (int r = 0; r < 4; r++)
                            s[r] = (kg + r <= qg) ? __builtin_amdgcn_exp2f(s[r]) : 0.f;
                    } else {
                        #pragma unroll
                        for (int r = 0; r < 4; r++)
                            s[r] = __builtin_amdgcn_exp2f(s[r]);
                    }
                    lsum[st] += s[0] + s[1] + s[2] + s[3];

                    union { unsigned u[2]; bf16x4 v; } pk;
                    pk.u[0] = __builtin_amdgcn_perm(fbits(s[1]), fbits(s[0]), 0x07060302u);
                    pk.u[1] = __builtin_amdgcn_perm(fbits(s[3]), fbits(s[2]), 0x07060302u);

                    #pragma unroll
                    for (int df = 0; df < 4; df++)
                        o_acc[st][df] = __builtin_amdgcn_mfma_f32_16x16x16bf16_1k(vf[df], pk.v, o_acc[st][df], 0, 0, 0);
                }
            }
        }

        // ---- store fp32 partials (additive across g) ----
        float* op = o_part + (size_t)g * OPART_STRIDE;
        #pragma unroll
        for (int st = 0; st < 2; st++) {
            float rs = lsum[st];
            rs += __shfl_xor(rs, 16);
            rs += __shfl_xor(rs, 32);
            int qg = qwbase + st * 16 + l16;
            if (quad == 0)
                l_part[g * 65536 + bh * SEQLEN + qg] = rs;
            #pragma unroll
            for (int df = 0; df < 4; df++)
                *(f32x4*)&op[((size_t)bh * SEQLEN + qg) * DKH + df * 16 + quad * 4] = o_acc[st][df];
        }
    }
}

// ---------- kernel 2b: combine split-K partials -> bf16 ao ----------
__global__ void combine_kernel(const float* __restrict__ o_part,
                               const float* __restrict__ l_part,
                               unsigned short* __restrict__ ao)
{
    int i = blockIdx.x * 256 + threadIdx.x;      // 0 .. 524287 (32 bh * 2048 q * 8 chunks)
    int bh = i >> 14, rem = i & 16383;
    int q = rem >> 3, c = (rem & 7) * 8;
    const float* p0 = o_part + ((size_t)bh * SEQLEN + q) * DKH + c;
    const float* p1 = p0 + OPART_STRIDE;
    float l = l_part[bh * SEQLEN + q] + l_part[65536 + bh * SEQLEN + q];
    float inv = 1.0f / l;
    float4 a0 = *(const float4*)p0, a1 = *(const float4*)(p0 + 4);
    float4 b0 = *(const float4*)p1, b1 = *(const float4*)(p1 + 4);
    ushort8 o;
    o[0] = f2bf((a0.x + b0.x) * inv); o[1] = f2bf((a0.y + b0.y) * inv);
    o[2] = f2bf((a0.z + b0.z) * inv); o[3] = f2bf((a0.w + b0.w) * inv);
    o[4] = f2bf((a1.x + b1.x) * inv); o[5] = f2bf((a1.y + b1.y) * inv);
    o[6] = f2bf((a1.z + b1.z) * inv); o[7] = f2bf((a1.w + b1.w) * inv);
    int b = bh >> 4, h = bh & 15;
    *(ushort8*)&ao[(size_t)(b * SEQLEN + q) * D_MODEL + h * DKH + c] = o;
}

// ---------- kernel 3: output projection (fp32 output) ----------
__global__ __launch_bounds__(256, 2)
void gemm_out(const unsigned short* __restrict__ AO,
              const unsigned short* __restrict__ Wo,
              float* __restrict__ out)
{
    __shared__ __align__(16) unsigned short a_lds[128 * 32];
    __shared__ __align__(16) unsigned short b_lds[128 * 32];

    const int m0 = blockIdx.x * 128, n0 = blockIdx.y * 128;
    f32x4 acc[4][4];
    gemm_core_128(AO, Wo, a_lds, b_lds, m0, n0, acc);

    const int lane = threadIdx.x & 63;
    const int w    = threadIdx.x >> 6;
    const int quad = lane >> 4;
    const int l16  = lane & 15;
    const int wm   = w & 1, wn = w >> 1;

    #pragma unroll
    for (int mi = 0; mi < 4; mi++)
        #pragma unroll
        for (int ni = 0; ni < 4; ni++)
            #pragma unroll
            for (int r = 0; r < 4; r++) {
                int row = m0 + wm * 64 + mi * 16 + quad * 4 + r;
                int col = n0 + wn * 64 + ni * 16 + l16;
                out[(size_t)row * D_MODEL + col] = acc[mi][ni][r];
            }
}

// ---------- launch ----------
extern "C" void kernel_launch(void* const* d_in, const int* in_sizes, int n_in,
                              void* d_out, int out_size, void* d_ws, size_t ws_size,
                              hipStream_t stream) {
    const float* X  = (const float*)d_in[0];
    const int*   pos = (const int*)d_in[1];
    const float* Wq = (const float*)d_in[2];
    const float* Wk = (const float*)d_in[3];
    const float* Wv = (const float*)d_in[4];
    const float* Wo = (const float*)d_in[5];
    float* out = (float*)d_out;

    // ws: Xb 8MB | Wqb..Wob 4x2MB | q/k/v 3x8MB | ao 8MB | tbl 512KB | o_part 33.5MB | l_part 512KB
    unsigned short* Xb  = (unsigned short*)d_ws;
    unsigned short* Wqb = Xb + 4194304;
    unsigned short* Wkb = Wqb + 1048576;
    unsigned short* Wvb = Wkb + 1048576;
    unsigned short* Wob = Wvb + 1048576;
    unsigned short* q_ws = Wob + 1048576;
    unsigned short* k_ws = q_ws + 4194304;
    unsigned short* v_ws = k_ws + 4194304;
    unsigned short* ao   = v_ws + 4194304;
    float2* tbl   = (float2*)(ao + 4194304);
    float* o_part = (float*)(tbl + 65536);
    float* l_part = o_part + 2 * OPART_STRIDE;

    cvt_all<<<dim3(2048, 6), dim3(256), 0, stream>>>(X, Wq, Wk, Wv, Wo, pos,
                                                     Xb, Wqb, Wkb, Wvb, Wob, tbl);
    gemm_qkv<<<dim3(32, 8, 3), dim3(256), 0, stream>>>(Xb, Wqb, Wkb, Wvb, tbl, q_ws, k_ws, v_ws);
    attn_kernel<<<dim3(32, 8, 2), dim3(256), 0, stream>>>(q_ws, k_ws, v_ws, o_part, l_part);
    combine_kernel<<<dim3(2048), dim3(256), 0, stream>>>(o_part, l_part, ao);
    gemm_out<<<dim3(32, 8), dim3(256), 0, stream>>>(ao, Wob, out);
}

// Round 11
// 170.668 us; speedup vs baseline: 1.0551x; 1.0551x over previous
//
#include <hip/hip_runtime.h>
#include <stdint.h>

#define D_MODEL 1024
#define NH      16
#define DKH     64
#define SEQLEN  2048
#define BATCH   2
#define KDIM    1024   // inner dim of all projections

typedef __attribute__((ext_vector_type(8))) short          short8;   // 8 bf16 (4 VGPRs)
typedef __attribute__((ext_vector_type(4))) short          bf16x4;   // 4 bf16 (2 VGPRs)
typedef __attribute__((ext_vector_type(8))) unsigned short ushort8;
typedef __attribute__((ext_vector_type(4))) unsigned short usht4;    // 'ushort4' is taken by HIP
typedef __attribute__((ext_vector_type(4))) float          f32x4;

// exp2(q·k) where q pre-scaled by 0.125*log2(e) == exp(q·k/8)
#define QSCALE 0.18033688011112042f

// ---------- helpers ----------
__device__ __forceinline__ unsigned short f2bf(float f) {
    union { float f; unsigned u; } v; v.f = f;
    unsigned u = v.u;
    unsigned r = (u + 0x7FFFu + ((u >> 16) & 1u)) >> 16;   // RNE
    return (unsigned short)r;
}
__device__ __forceinline__ unsigned fbits(float f) {
    union { float f; unsigned u; } v; v.f = f; return v.u;
}

__device__ __forceinline__ void gload_lds16(const unsigned short* g, unsigned short* l) {
    __builtin_amdgcn_global_load_lds(
        (__attribute__((address_space(1))) void*)(g),
        (__attribute__((address_space(3))) void*)(l), 16, 0, 0);
}

// ---------- kernel 0: fp32 -> bf16 convert (5 tensors) + RoPE cos/sin table ----------
__global__ void cvt_all(const float* __restrict__ X,  const float* __restrict__ Wq,
                        const float* __restrict__ Wk, const float* __restrict__ Wv,
                        const float* __restrict__ Wo, const int* __restrict__ pos,
                        unsigned short* __restrict__ Xb,  unsigned short* __restrict__ Wqb,
                        unsigned short* __restrict__ Wkb, unsigned short* __restrict__ Wvb,
                        unsigned short* __restrict__ Wob, float2* __restrict__ tbl) {
    const int z = blockIdx.y;
    if (z == 5) {
        int i = blockIdx.x * 256 + threadIdx.x;   // tbl[s][j], 2048*32 entries
        if (i < 65536) {
            int s = i >> 5, j = i & 31;
            float freq = expf(-((float)(2 * j) * (1.0f / 64.0f)) * 9.210340371976184f);
            float ang = (float)pos[s] * freq;
            float sn, cn;
            sincosf(ang, &sn, &cn);
            tbl[i] = make_float2(cn, sn);
        }
        return;
    }
    const float* src; unsigned short* dst; int n;
    if (z == 0)      { src = X;  dst = Xb;  n = 4194304; }
    else if (z == 1) { src = Wq; dst = Wqb; n = 1048576; }
    else if (z == 2) { src = Wk; dst = Wkb; n = 1048576; }
    else if (z == 3) { src = Wv; dst = Wvb; n = 1048576; }
    else             { src = Wo; dst = Wob; n = 1048576; }
    int i = (blockIdx.x * 256 + threadIdx.x) * 8;
    if (i >= n) return;
    float4 a = *(const float4*)(src + i);
    float4 b = *(const float4*)(src + i + 4);
    ushort8 o;
    o[0] = f2bf(a.x); o[1] = f2bf(a.y); o[2] = f2bf(a.z); o[3] = f2bf(a.w);
    o[4] = f2bf(b.x); o[5] = f2bf(b.y); o[6] = f2bf(b.z); o[7] = f2bf(b.w);
    *(ushort8*)(dst + i) = o;
}

// ---------- shared GEMM core: C[128x128] = A[m0:,:] * W[n0:,:]^T, K=1024, BK=64 ----------
// 16 K-iterations (half the barriers of BK=32). LDS rows are 128B so naive frag reads
// would be 16-way bank-conflicted; fixed by XOR-swizzling the GLOBAL source colgroup
// during global_load_lds staging (LDS dest is fixed lane-order) and applying the same
// xor on fragment reads: slot s of row r holds global k-group (s ^ (r&7)).
__device__ __forceinline__ void gemm_core_128(
    const unsigned short* __restrict__ A, const unsigned short* __restrict__ W,
    unsigned short* a_lds, unsigned short* b_lds,
    int m0, int n0, f32x4 acc[4][4])
{
    const int tid  = threadIdx.x;
    const int lane = tid & 63;
    const int w    = tid >> 6;
    const int quad = lane >> 4;
    const int l16  = lane & 15;
    const int wm   = w & 1, wn = w >> 1;

    const int row_in = lane >> 3;                 // 0..7 row within 8-row chunk
    const int cg     = ((lane & 7) ^ row_in) * 8; // xor-swizzled k-group offset (elems)

    #pragma unroll
    for (int mi = 0; mi < 4; mi++)
        #pragma unroll
        for (int ni = 0; ni < 4; ni++) {
            f32x4 z = {0.f, 0.f, 0.f, 0.f};
            acc[mi][ni] = z;
        }

    const int x7 = l16 & 7;                       // = row&7 for all frag rows

    for (int kk = 0; kk < KDIM; kk += 64) {
        __syncthreads();
        #pragma unroll
        for (int j = 0; j < 4; ++j) {
            int c = w * 4 + j;                    // chunk: 8 rows x 64 k (1KB)
            gload_lds16(A + (size_t)(m0 + c * 8 + row_in) * KDIM + kk + cg, &a_lds[c * 512]);
            gload_lds16(W + (size_t)(n0 + c * 8 + row_in) * KDIM + kk + cg, &b_lds[c * 512]);
        }
        __syncthreads();

        short8 af[2][4], bf[2][4];
        #pragma unroll
        for (int kk2 = 0; kk2 < 2; kk2++)
            #pragma unroll
            for (int i = 0; i < 4; i++) {
                int g = (kk2 * 4 + quad) ^ x7;    // de-swizzle
                af[kk2][i] = *(const short8*)&a_lds[(wm * 64 + i * 16 + l16) * 64 + g * 8];
                bf[kk2][i] = *(const short8*)&b_lds[(wn * 64 + i * 16 + l16) * 64 + g * 8];
            }
        #pragma unroll
        for (int kk2 = 0; kk2 < 2; kk2++)
            #pragma unroll
            for (int mi = 0; mi < 4; mi++)
                #pragma unroll
                for (int ni = 0; ni < 4; ni++)
                    acc[mi][ni] = __builtin_amdgcn_mfma_f32_16x16x32_bf16(af[kk2][mi], bf[kk2][ni], acc[mi][ni], 0, 0, 0);
    }
}

// ---------- kernel 1: QKV projection + fused RoPE (Q,K) + V^T transpose-store ----------
__global__ __launch_bounds__(256, 2)
void gemm_qkv(const unsigned short* __restrict__ X,
              const unsigned short* __restrict__ Wq,
              const unsigned short* __restrict__ Wk,
              const unsigned short* __restrict__ Wv,
              const float2* __restrict__ tbl,
              unsigned short* __restrict__ q_ws,
              unsigned short* __restrict__ k_ws,
              unsigned short* __restrict__ v_ws)
{
    __shared__ __align__(16) unsigned short a_lds[128 * 64];
    __shared__ __align__(16) unsigned short b_lds[128 * 64];
    __shared__ __align__(16) unsigned short t_lds[32 * 136];   // V transpose staging

    const int z = blockIdx.z;
    const unsigned short* W = (z == 0) ? Wq : ((z == 1) ? Wk : Wv);
    const int m0 = blockIdx.x * 128, n0 = blockIdx.y * 128;

    f32x4 acc[4][4];
    gemm_core_128(X, W, a_lds, b_lds, m0, n0, acc);

    const int tid  = threadIdx.x;
    const int lane = tid & 63;
    const int w    = tid >> 6;
    const int quad = lane >> 4;
    const int l16  = lane & 15;
    const int wm   = w & 1, wn = w >> 1;

    if (z == 2) {
        // ---- V: transpose 128x128 tile through LDS, store [bh][d][s] coalesced ----
        const int bx = m0 >> 11;                 // batch
        const int c_local_w = wn * 16 + l16;     // writer column slot 0..31
        const int rd_c = tid >> 3;               // reader column slot 0..31
        const int rd_s = (tid & 7) * 16;         // reader s-offset
        #pragma unroll
        for (int ni = 0; ni < 4; ni++) {
            __syncthreads();                     // prior pass reads (or GEMM reads) done
            #pragma unroll
            for (int mi = 0; mi < 4; mi++) {
                usht4 v4;
                #pragma unroll
                for (int r = 0; r < 4; r++) v4[r] = f2bf(acc[mi][ni][r]);
                *(usht4*)&t_lds[c_local_w * 136 + wm * 64 + mi * 16 + quad * 4] = v4;
            }
            __syncthreads();
            int col = n0 + (rd_c >> 4) * 64 + ni * 16 + (rd_c & 15);
            int h = col >> 6, d = col & 63;
            size_t base = (size_t)(bx * NH + h) * DKH * SEQLEN + (size_t)d * SEQLEN
                        + (m0 & 2047) + rd_s;
            ushort8 x0 = *(ushort8*)&t_lds[rd_c * 136 + rd_s];
            ushort8 x1 = *(ushort8*)&t_lds[rd_c * 136 + rd_s + 8];
            *(ushort8*)&v_ws[base]     = x0;
            *(ushort8*)&v_ws[base + 8] = x1;
        }
    } else {
        // ---- Q/K: fused RoPE on fp32 acc, then round once ----
        unsigned short* dst = (z == 0) ? q_ws : k_ws;
        const float sc = (z == 0) ? QSCALE : 1.0f;
        #pragma unroll
        for (int mi = 0; mi < 4; mi++)
            #pragma unroll
            for (int ni = 0; ni < 4; ni++)
                #pragma unroll
                for (int r = 0; r < 4; r++) {
                    int row = m0 + wm * 64 + mi * 16 + quad * 4 + r;
                    int col = n0 + wn * 64 + ni * 16 + l16;
                    int b = row >> 11, s = row & 2047;
                    int h = col >> 6,  d = col & 63;
                    float val = acc[mi][ni][r];
                    float other = __shfl_xor(val, 1);     // RoPE partner: col^1 == lane^1
                    float2 cs = tbl[s * 32 + (d >> 1)];
                    float rv = (d & 1) ? (other * cs.y + val * cs.x)
                                       : (val * cs.x - other * cs.y);
                    dst[(size_t)(b * NH + h) * SEQLEN * DKH + (size_t)s * DKH + d] =
                        f2bf(rv * sc);
                }
    }
}

// ---------- kernel 2: causal flash attention (S^T trick; 128q x 128k blocks) ----------
// grid (bh=32, p=8): id%8 = bh%8 -> all 8 p-blocks of a bh on one XCD (L2 locality).
// Block p does q-supertiles (15-p) then p => balanced 17 key-tile iterations.
// S^T = K·Q^T: C-layout lane holds P[q=l16][key=quad*4+r] == B-operand layout of
// mfma_16x16x16 -> PV without cross-lane transform. O^T in C-layout.
__global__ __launch_bounds__(256, 2)
void attn_kernel(const unsigned short* __restrict__ q_ws,
                 const unsigned short* __restrict__ k_ws,
                 const unsigned short* __restrict__ v_ws,
                 unsigned short* __restrict__ ao)
{
    __shared__ __align__(16) unsigned short k_lds[128 * 72];       // [key][d] pad->72
    __shared__ __align__(16) unsigned short v_lds[64 * 136];       // [d][key] pad->136

    const int bh  = blockIdx.x;
    const int p   = blockIdx.y;         // 0..7
    const int tid = threadIdx.x, lane = tid & 63, w = tid >> 6;
    const int quad = lane >> 4, l16 = lane & 15;

    const size_t kqbase = (size_t)bh * SEQLEN * DKH;
    const size_t vbase  = (size_t)bh * DKH * SEQLEN;
    const int b = bh >> 4, h = bh & 15;

    const int krow = tid >> 3, kcol = (tid & 7) * 8;
    const int vrow = tid >> 4, vcol = (tid & 15) * 8;

    #pragma unroll
    for (int phase = 0; phase < 2; ++phase) {
        const int qt2 = (phase == 0) ? (15 - p) : p;
        const int q0  = qt2 * 128;
        const int nt  = qt2 + 1;              // # of 128-key tiles
        const int qwbase = q0 + w * 32;       // this wave's 32 queries

        short8 aq[2][2];
        #pragma unroll
        for (int st = 0; st < 2; st++)
            #pragma unroll
            for (int kc = 0; kc < 2; kc++)
                aq[st][kc] = *(const short8*)(q_ws + kqbase +
                    (size_t)(qwbase + st * 16 + l16) * DKH + kc * 32 + quad * 8);

        f32x4 o_acc[2][4];
        #pragma unroll
        for (int st = 0; st < 2; st++)
            #pragma unroll
            for (int df = 0; df < 4; df++) { f32x4 z = {0.f,0.f,0.f,0.f}; o_acc[st][df] = z; }
        float lsum[2] = {0.f, 0.f};

        // prefetch tile 0
        ushort8 kreg[4], vreg[4];
        #pragma unroll
        for (int rr = 0; rr < 4; ++rr) {
            kreg[rr] = *(const ushort8*)(k_ws + kqbase + (size_t)(krow + rr * 32) * DKH + kcol);
            vreg[rr] = *(const ushort8*)(v_ws + vbase + (size_t)(vrow + rr * 16) * SEQLEN + vcol);
        }

        for (int t = 0; t < nt; ++t) {
            const int s0 = t * 128;
            __syncthreads();
            #pragma unroll
            for (int rr = 0; rr < 4; ++rr) {
                *(ushort8*)&k_lds[(krow + rr * 32) * 72 + kcol]  = kreg[rr];
                *(ushort8*)&v_lds[(vrow + rr * 16) * 136 + vcol] = vreg[rr];
            }
            __syncthreads();
            if (t < nt - 1) {
                int s1 = s0 + 128;
                #pragma unroll
                for (int rr = 0; rr < 4; ++rr) {
                    kreg[rr] = *(const ushort8*)(k_ws + kqbase + (size_t)(s1 + krow + rr * 32) * DKH + kcol);
                    vreg[rr] = *(const ushort8*)(v_ws + vbase + (size_t)(vrow + rr * 16) * SEQLEN + s1 + vcol);
                }
            }

            const bool diag = (t == nt - 1);
            #pragma unroll
            for (int nf = 0; nf < 8; nf++) {
                short8 kf0 = *(const short8*)&k_lds[(nf * 16 + l16) * 72 + 0 * 32 + quad * 8];
                short8 kf1 = *(const short8*)&k_lds[(nf * 16 + l16) * 72 + 1 * 32 + quad * 8];
                bf16x4 vf[4];
                #pragma unroll
                for (int df = 0; df < 4; df++)
                    vf[df] = *(const bf16x4*)&v_lds[(df * 16 + l16) * 136 + nf * 16 + quad * 4];

                #pragma unroll
                for (int st = 0; st < 2; st++) {
                    f32x4 s = {0.f,0.f,0.f,0.f};
                    s = __builtin_amdgcn_mfma_f32_16x16x32_bf16(kf0, aq[st][0], s, 0, 0, 0);
                    s = __builtin_amdgcn_mfma_f32_16x16x32_bf16(kf1, aq[st][1], s, 0, 0, 0);

                    if (diag) {
                        int qg = qwbase + st * 16 + l16;
                        int kg = s0 + nf * 16 + quad * 4;
                        #pragma unroll
                        for (int r = 0; r < 4; r++)
                            s[r] = (kg + r <= qg) ? __builtin_amdgcn_exp2f(s[r]) : 0.f;
                    } else {
                        #pragma unroll
                        for (int r = 0; r < 4; r++)
                            s[r] = __builtin_amdgcn_exp2f(s[r]);
                    }
                    lsum[st] += s[0] + s[1] + s[2] + s[3];

                    union { unsigned u[2]; bf16x4 v; } pk;
                    pk.u[0] = __builtin_amdgcn_perm(fbits(s[1]), fbits(s[0]), 0x07060302u);
                    pk.u[1] = __builtin_amdgcn_perm(fbits(s[3]), fbits(s[2]), 0x07060302u);

                    #pragma unroll
                    for (int df = 0; df < 4; df++)
                        o_acc[st][df] = __builtin_amdgcn_mfma_f32_16x16x16bf16_1k(vf[df], pk.v, o_acc[st][df], 0, 0, 0);
                }
            }
        }

        // epilogue per strip
        #pragma unroll
        for (int st = 0; st < 2; st++) {
            float rs = lsum[st];
            rs += __shfl_xor(rs, 16);
            rs += __shfl_xor(rs, 32);
            float inv = 1.0f / rs;
            int qg = qwbase + st * 16 + l16;
            #pragma unroll
            for (int df = 0; df < 4; df++) {
                usht4 ov;
                #pragma unroll
                for (int r = 0; r < 4; r++) ov[r] = f2bf(o_acc[st][df][r] * inv);
                *(usht4*)&ao[(size_t)(b * SEQLEN + qg) * D_MODEL + h * DKH + df * 16 + quad * 4] = ov;
            }
        }
    }
}

// ---------- kernel 3: output projection (fp32 output) ----------
__global__ __launch_bounds__(256, 2)
void gemm_out(const unsigned short* __restrict__ AO,
              const unsigned short* __restrict__ Wo,
              float* __restrict__ out)
{
    __shared__ __align__(16) unsigned short a_lds[128 * 64];
    __shared__ __align__(16) unsigned short b_lds[128 * 64];

    const int m0 = blockIdx.x * 128, n0 = blockIdx.y * 128;
    f32x4 acc[4][4];
    gemm_core_128(AO, Wo, a_lds, b_lds, m0, n0, acc);

    const int lane = threadIdx.x & 63;
    const int w    = threadIdx.x >> 6;
    const int quad = lane >> 4;
    const int l16  = lane & 15;
    const int wm   = w & 1, wn = w >> 1;

    #pragma unroll
    for (int mi = 0; mi < 4; mi++)
        #pragma unroll
        for (int ni = 0; ni < 4; ni++)
            #pragma unroll
            for (int r = 0; r < 4; r++) {
                int row = m0 + wm * 64 + mi * 16 + quad * 4 + r;
                int col = n0 + wn * 64 + ni * 16 + l16;
                out[(size_t)row * D_MODEL + col] = acc[mi][ni][r];
            }
}

// ---------- launch ----------
extern "C" void kernel_launch(void* const* d_in, const int* in_sizes, int n_in,
                              void* d_out, int out_size, void* d_ws, size_t ws_size,
                              hipStream_t stream) {
    const float* X  = (const float*)d_in[0];
    const int*   pos = (const int*)d_in[1];
    const float* Wq = (const float*)d_in[2];
    const float* Wk = (const float*)d_in[3];
    const float* Wv = (const float*)d_in[4];
    const float* Wo = (const float*)d_in[5];
    float* out = (float*)d_out;

    // ws (ushorts): Xb 4M | Wqb 1M | Wkb 1M | Wvb 1M | Wob 1M | q 4M | k 4M | v^T 4M | ao 4M | tbl 512KB
    unsigned short* Xb  = (unsigned short*)d_ws;
    unsigned short* Wqb = Xb + 4194304;
    unsigned short* Wkb = Wqb + 1048576;
    unsigned short* Wvb = Wkb + 1048576;
    unsigned short* Wob = Wvb + 1048576;
    unsigned short* q_ws = Wob + 1048576;
    unsigned short* k_ws = q_ws + 4194304;
    unsigned short* v_ws = k_ws + 4194304;
    unsigned short* ao   = v_ws + 4194304;
    float2* tbl = (float2*)(ao + 4194304);

    cvt_all<<<dim3(2048, 6), dim3(256), 0, stream>>>(X, Wq, Wk, Wv, Wo, pos,
                                                     Xb, Wqb, Wkb, Wvb, Wob, tbl);
    gemm_qkv<<<dim3(32, 8, 3), dim3(256), 0, stream>>>(Xb, Wqb, Wkb, Wvb, tbl, q_ws, k_ws, v_ws);
    attn_kernel<<<dim3(32, 8), dim3(256), 0, stream>>>(q_ws, k_ws, v_ws, ao);
    gemm_out<<<dim3(32, 8), dim3(256), 0, stream>>>(ao, Wob, out);
}